// Round 2
// baseline (206.253 us; speedup 1.0000x reference)
//
#include <hip/hip_runtime.h>
#include <hip/hip_bf16.h>
#include <stdint.h>

using bf16 = __hip_bfloat16;
typedef __attribute__((ext_vector_type(8))) short short8;
typedef __attribute__((ext_vector_type(4))) float f32x4;

#define BM 128
#define BK 32

// -------- async global->LDS, 16B per lane (m97 pattern) --------
__device__ __forceinline__ void g2lds16(const void* g, void* l) {
    __builtin_amdgcn_global_load_lds(
        (const __attribute__((address_space(1))) void*)g,
        (__attribute__((address_space(3))) void*)l,
        16, 0, 0);
}

__device__ __forceinline__ short f2bs(float x) {
    union { bf16 h; short s; } u;
    u.h = __float2bfloat16(x);
    return u.s;
}

// ---- LDS XOR swizzles (conflict-free fragment reads) ----
// bf16 tile [rows][32 bf16] = 4 groups/row of 8 bf16 (16B). s=(row>>1)&3.
__device__ __forceinline__ int bswz(int row, int cg) { return cg ^ ((row >> 1) & 3); }
// fp32 tile [rows][32 f32] = 8 groups/row of 4 f32 (16B). s=row&7.
__device__ __forceinline__ int fswz(int row, int cg) { return cg ^ (row & 7); }

// ---- fp32 -> bf16 64x64 tile transpose (+ optional row-major bf16 copy) ----
__global__ __launch_bounds__(256)
void transpose_cvt(const float* __restrict__ src, ushort* __restrict__ dstT,
                   ushort* __restrict__ dstN,
                   int R, int C, long sstride, long dstrideT, long dstrideN)
{
    __shared__ __align__(16) ushort t[64][72];
    const float* s = src + (size_t)blockIdx.z * sstride;
    ushort*      dT = dstT + (size_t)blockIdx.z * dstrideT;
    const int r0 = blockIdx.y * 64, c0 = blockIdx.x * 64;
    const int tid = threadIdx.x;
#pragma unroll
    for (int ii = 0; ii < 4; ++ii) {
        int idx = ii * 256 + tid;
        int r = idx >> 4, c4 = (idx & 15) * 4;
        float4 v = *(const float4*)&s[(size_t)(r0 + r) * C + c0 + c4];
        union { ushort u[4]; uint2 q; } o;
        o.u[0] = (ushort)f2bs(v.x); o.u[1] = (ushort)f2bs(v.y);
        o.u[2] = (ushort)f2bs(v.z); o.u[3] = (ushort)f2bs(v.w);
        *(uint2*)&t[r][c4] = o.q;
        if (dstN) {
            ushort* dN = dstN + (size_t)blockIdx.z * dstrideN;
            *(uint2*)&dN[(size_t)(r0 + r) * C + c0 + c4] = o.q;
        }
    }
    __syncthreads();
#pragma unroll
    for (int ii = 0; ii < 2; ++ii) {
        int idx = ii * 256 + tid;
        int c = idx >> 3, r8 = (idx & 7) * 8;
        union { ushort u[8]; uint4 v; } tmp;
#pragma unroll
        for (int j = 0; j < 8; ++j) tmp.u[j] = t[r8 + j][c];
        *(uint4*)&dT[(size_t)(c0 + c) * R + r0 + r8] = tmp.v;
    }
}

// -------- C = A * B^T ; A:[M][K], B:[N][K] row-major, k contiguous --------
// MODE 0: bf16 store. MODE 1: fp32 atomicAdd (split-K). MODE 2: fp32 store.
// A_F32: A operand fp32 in global (staged fp32, cvt at frag load).
// NFRAG: n-fragments (16-wide) per wave; BN = 32*NFRAG. Waves 2x2,
//        wave tile 64 x (16*NFRAG).
template <int MODE, int A_F32, int NFRAG>
__global__ __launch_bounds__(256)
void gemm_bt(const void* __restrict__ Av, const bf16* __restrict__ B,
             void* __restrict__ Cv, int M, int N, int K, int kChunks,
             long sA, long sB, long sC)
{
    constexpr int BN  = 32 * NFRAG;
    constexpr int BSH = BN / 64;            // B staging shots (256x16B each)
    __shared__ __align__(16) bf16 lA[BM * BK * (A_F32 ? 2 : 1)];
    __shared__ __align__(16) bf16 lB[BN * BK];

    const int z     = blockIdx.z;
    const int batch = z / kChunks;
    const int chunk = z - batch * kChunks;
    const int kLen  = K / kChunks;
    const int k0    = chunk * kLen;

    const int m0 = blockIdx.y * BM;
    const int n0 = blockIdx.x * BN;

    const int tid  = threadIdx.x;
    const int lane = tid & 63;
    const int wave = tid >> 6;
    const int wr   = wave >> 1, wc = wave & 1;
    const int ml   = lane & 15;
    const int q    = lane >> 4;

    // B staging pointers (swizzled)
    const bf16* Bb = B + (size_t)batch * sB;
    const bf16* bp[BSH];
#pragma unroll
    for (int s = 0; s < BSH; ++s) {
        int idx = s * 256 + tid;
        int row = idx >> 2, cg = idx & 3;
        bp[s] = Bb + (size_t)(n0 + row) * K + k0 + 8 * bswz(row, cg);
    }

    // A staging pointers (swizzled)
    const float* a32[4];
    const bf16*  a16[2];
    if constexpr (A_F32) {
        const float* Ab = (const float*)Av + (size_t)batch * sA;
#pragma unroll
        for (int s = 0; s < 4; ++s) {
            int idx = s * 256 + tid;
            int row = idx >> 3, cg = idx & 7;
            a32[s] = Ab + (size_t)(m0 + row) * K + k0 + 4 * fswz(row, cg);
        }
    } else {
        const bf16* Ab = (const bf16*)Av + (size_t)batch * sA;
#pragma unroll
        for (int s = 0; s < 2; ++s) {
            int idx = s * 256 + tid;
            int row = idx >> 2, cg = idx & 3;
            a16[s] = Ab + (size_t)(m0 + row) * K + k0 + 8 * bswz(row, cg);
        }
    }

    f32x4 acc[4][NFRAG] = {};

    const int nk = kLen / BK;
    for (int kt = 0; kt < nk; ++kt) {
        if constexpr (A_F32) {
            float* lAf = (float*)lA;
#pragma unroll
            for (int s = 0; s < 4; ++s) {
                g2lds16(a32[s], &lAf[(s * 256 + tid) * 4]);
                a32[s] += BK;
            }
        } else {
#pragma unroll
            for (int s = 0; s < 2; ++s) {
                g2lds16(a16[s], &lA[(s * 256 + tid) * 8]);
                a16[s] += BK;
            }
        }
#pragma unroll
        for (int s = 0; s < BSH; ++s) {
            g2lds16(bp[s], &lB[(s * 256 + tid) * 8]);
            bp[s] += BK;
        }
        __syncthreads();

        short8 af[4], bfr[NFRAG];
#pragma unroll
        for (int i = 0; i < 4; ++i) {
            const int rA = wr * 64 + i * 16 + ml;
            if constexpr (A_F32) {
                const float* lAf = (const float*)lA;
                float4 x0 = *(const float4*)&lAf[rA * 32 + 4 * fswz(rA, 2 * q)];
                float4 x1 = *(const float4*)&lAf[rA * 32 + 4 * fswz(rA, 2 * q + 1)];
                af[i][0] = f2bs(x0.x); af[i][1] = f2bs(x0.y);
                af[i][2] = f2bs(x0.z); af[i][3] = f2bs(x0.w);
                af[i][4] = f2bs(x1.x); af[i][5] = f2bs(x1.y);
                af[i][6] = f2bs(x1.z); af[i][7] = f2bs(x1.w);
            } else {
                af[i] = *(const short8*)&lA[rA * 32 + 8 * bswz(rA, q)];
            }
        }
#pragma unroll
        for (int j = 0; j < NFRAG; ++j) {
            const int rB = wc * (16 * NFRAG) + j * 16 + ml;
            bfr[j] = *(const short8*)&lB[rB * 32 + 8 * bswz(rB, q)];
        }
#pragma unroll
        for (int mi = 0; mi < 4; ++mi)
#pragma unroll
            for (int nj = 0; nj < NFRAG; ++nj)
                acc[mi][nj] = __builtin_amdgcn_mfma_f32_16x16x32_bf16(
                    af[mi], bfr[nj], acc[mi][nj], 0, 0, 0);
        __syncthreads();
    }

    // epilogue: C/D layout col=lane&15, row=(lane>>4)*4+r (m89-verified)
#pragma unroll
    for (int mi = 0; mi < 4; ++mi)
#pragma unroll
        for (int nj = 0; nj < NFRAG; ++nj)
#pragma unroll
            for (int r = 0; r < 4; ++r) {
                int row = m0 + wr * 64 + mi * 16 + q * 4 + r;
                int col = n0 + wc * (16 * NFRAG) + nj * 16 + ml;
                if constexpr (MODE == 1) {
                    float* Cf = (float*)Cv + (size_t)batch * sC;
                    atomicAdd(&Cf[(size_t)row * N + col], acc[mi][nj][r]);
                } else if constexpr (MODE == 0) {
                    ushort* Cb = (ushort*)Cv + (size_t)batch * sC;
                    Cb[(size_t)row * N + col] = (ushort)f2bs(acc[mi][nj][r]);
                } else {
                    float* Cf = (float*)Cv + (size_t)batch * sC;
                    Cf[(size_t)row * N + col] = acc[mi][nj][r];
                }
            }
}

// ---------------------------------------------------------------
// fp32 I/O.  O = ((X W^T) X^T) X == X * (W^T (X^T X))   [associative]
//   G  = Xt * Xt^T   (split-K=4, fp32 atomic)     Xt = bf16(X)^T
//   Mt = Gf * Wt^T   (A fp32 staged, bf16 store)  Wt = bf16(W)^T
//   O  = X * Mt^T    (fp32 store; A = Xb bf16 if ws fits, else X fp32)
// d_out scratch (dead before step 7 overwrites):
//   Xt bf16 @0 (16M) | Gf f32 @16M (8M) | Wt @28M (2M)
// ws: [Xb bf16 16M if ws_size>=20M] + Mt bf16 4M.
// Round 1: NFRAG=4 (BN=128, verified m97 geometry) on the two 17 GF
// GEMMs (steps 4,7); step 6 reads Gf fp32 directly (cvt kernel dropped).
// ---------------------------------------------------------------
extern "C" void kernel_launch(void* const* d_in, const int* in_sizes, int n_in,
                              void* d_out, int out_size, void* d_ws, size_t ws_size,
                              hipStream_t stream)
{
    const int B = 2, N = 4096, D = 1024;
    const float* X = (const float*)d_in[0];   // [B][N][D] fp32
    const float* W = (const float*)d_in[1];   // [D][D]    fp32
    float* out = (float*)d_out;               // [B][N][D] fp32

    char* ob = (char*)d_out;
    char* ws = (char*)d_ws;
    ushort* Xt = (ushort*)ob;                  // [B][D][N] bf16, 16 MiB
    float*  Gf = (float*)(ob + (16ll << 20));  // [B][D][D] fp32,  8 MiB
    ushort* Wt = (ushort*)(ob + (28ll << 20)); // [D][D]    bf16,  2 MiB

    const bool bigws = ws_size >= (20ull << 20);
    ushort* Xb = bigws ? (ushort*)ws : nullptr;             // [B][N][D] bf16, 16 MiB
    ushort* Mt = (ushort*)(ws + (bigws ? (16ll << 20) : 0)); // [B][D][D] bf16, 4 MiB

    // 1) Xt[b] = bf16(X[b])^T  (+ Xb = bf16(X) row-major when ws allows)
    transpose_cvt<<<dim3(D / 64, N / 64, B), 256, 0, stream>>>(
        X, Xt, Xb, N, D, (long)N * D, (long)D * N, (long)N * D);
    // 2) Wt = bf16(W)^T
    transpose_cvt<<<dim3(D / 64, D / 64, 1), 256, 0, stream>>>(
        W, Wt, nullptr, D, D, 0, 0, 0);
    // 3) zero split-K accumulator
    (void)hipMemsetAsync(Gf, 0, (size_t)B * D * D * sizeof(float), stream);
    // 4) Gf[b] += Xt[b] * Xt[b]^T   (M=N=D, K=4096, split-K 4, BN=128)
    gemm_bt<1, 0, 4><<<dim3(D / 128, D / BM, B * 4), 256, 0, stream>>>(
        (const void*)Xt, (const bf16*)Xt, Gf, D, D, N, 4,
        (long)D * N, (long)D * N, (long)D * D);
    // 6) Mt[b] = Gf[b] * Wt^T   (M=N=K=D, BN=64, A fp32 staged)
    gemm_bt<0, 1, 2><<<dim3(D / 64, D / BM, B), 256, 0, stream>>>(
        (const void*)Gf, (const bf16*)Wt, Mt, D, D, D, 1,
        (long)D * D, 0, (long)D * D);
    // 7) O[b] = X[b] * Mt[b]^T  (M=4096, N=D, K=D, BN=128; overwrites d_out)
    if (bigws) {
        gemm_bt<2, 0, 4><<<dim3(D / 128, N / BM, B), 256, 0, stream>>>(
            (const void*)Xb, (const bf16*)Mt, out, N, D, D, 1,
            (long)N * D, (long)D * D, (long)N * D);
    } else {
        gemm_bt<2, 1, 4><<<dim3(D / 128, N / BM, B), 256, 0, stream>>>(
            (const void*)X, (const bf16*)Mt, out, N, D, D, 1,
            (long)N * D, (long)D * D, (long)N * D);
    }
}

// Round 3
// 203.099 us; speedup vs baseline: 1.0155x; 1.0155x over previous
//
#include <hip/hip_runtime.h>
#include <hip/hip_bf16.h>
#include <stdint.h>

using bf16 = __hip_bfloat16;
typedef __attribute__((ext_vector_type(8))) short short8;
typedef __attribute__((ext_vector_type(4))) float f32x4;

#define BM 128
#define BK 32

// -------- async global->LDS, 16B per lane (m97 pattern) --------
__device__ __forceinline__ void g2lds16(const void* g, void* l) {
    __builtin_amdgcn_global_load_lds(
        (const __attribute__((address_space(1))) void*)g,
        (__attribute__((address_space(3))) void*)l,
        16, 0, 0);
}

__device__ __forceinline__ short f2bs(float x) {
    union { bf16 h; short s; } u;
    u.h = __float2bfloat16(x);
    return u.s;
}

// ---- LDS XOR swizzles (conflict-free fragment reads) ----
// bf16 tile [rows][32 bf16] = 4 groups/row of 8 bf16 (16B). s=(row>>1)&3.
__device__ __forceinline__ int bswz(int row, int cg) { return cg ^ ((row >> 1) & 3); }
// fp32 tile [rows][32 f32] = 8 groups/row of 4 f32 (16B). s=row&7.
__device__ __forceinline__ int fswz(int row, int cg) { return cg ^ (row & 7); }

// ---- fp32 -> bf16 64x64 tile transpose (+ optional row-major bf16 copy) ----
__global__ __launch_bounds__(256)
void transpose_cvt(const float* __restrict__ src, ushort* __restrict__ dstT,
                   ushort* __restrict__ dstN,
                   int R, int C, long sstride, long dstrideT, long dstrideN)
{
    __shared__ __align__(16) ushort t[64][72];
    const float* s = src + (size_t)blockIdx.z * sstride;
    ushort*      dT = dstT + (size_t)blockIdx.z * dstrideT;
    const int r0 = blockIdx.y * 64, c0 = blockIdx.x * 64;
    const int tid = threadIdx.x;
#pragma unroll
    for (int ii = 0; ii < 4; ++ii) {
        int idx = ii * 256 + tid;
        int r = idx >> 4, c4 = (idx & 15) * 4;
        float4 v = *(const float4*)&s[(size_t)(r0 + r) * C + c0 + c4];
        union { ushort u[4]; uint2 q; } o;
        o.u[0] = (ushort)f2bs(v.x); o.u[1] = (ushort)f2bs(v.y);
        o.u[2] = (ushort)f2bs(v.z); o.u[3] = (ushort)f2bs(v.w);
        *(uint2*)&t[r][c4] = o.q;
        if (dstN) {
            ushort* dN = dstN + (size_t)blockIdx.z * dstrideN;
            *(uint2*)&dN[(size_t)(r0 + r) * C + c0 + c4] = o.q;
        }
    }
    __syncthreads();
#pragma unroll
    for (int ii = 0; ii < 2; ++ii) {
        int idx = ii * 256 + tid;
        int c = idx >> 3, r8 = (idx & 7) * 8;
        union { ushort u[8]; uint4 v; } tmp;
#pragma unroll
        for (int j = 0; j < 8; ++j) tmp.u[j] = t[r8 + j][c];
        *(uint4*)&dT[(size_t)(c0 + c) * R + r0 + r8] = tmp.v;
    }
}

// -------- C = A * B^T ; A:[M][K], B:[N][K] row-major, k contiguous --------
// MODE 0: bf16 store. MODE 1: fp32 atomicAdd (split-K). MODE 2: fp32 store.
// A_F32: A operand fp32 in global (staged fp32, cvt at frag load).
// NFRAG: n-fragments (16-wide) per wave; BN = 32*NFRAG.
// Round 2: T3-minimum double-buffer pipeline (stage t+1 before compute t,
// ONE barrier per K-step) + chunked XCD swizzle (requires gx*gy % 8 == 0).
template <int MODE, int A_F32, int NFRAG>
__global__ __launch_bounds__(256)
void gemm_bt(const void* __restrict__ Av, const bf16* __restrict__ B,
             void* __restrict__ Cv, int M, int N, int K, int kChunks,
             long sA, long sB, long sC)
{
    constexpr int BN  = 32 * NFRAG;
    constexpr int BSH = BN / 64;            // B staging shots (256x16B each)
    constexpr int ANE = BM * BK * (A_F32 ? 2 : 1);  // bf16 elems per A buffer
    __shared__ __align__(16) bf16 lA[2][ANE];
    __shared__ __align__(16) bf16 lB[2][BN * BK];

    const int z     = blockIdx.z;
    const int batch = z / kChunks;
    const int chunk = z - batch * kChunks;
    const int kLen  = K / kChunks;
    const int k0    = chunk * kLen;

    // XCD-aware chunked swizzle of flattened (x,y); bijective since nxy%8==0
    const int gx  = gridDim.x;
    int flat = blockIdx.y * gx + blockIdx.x;
    const int cpx = (gx * gridDim.y) >> 3;
    flat = (flat & 7) * cpx + (flat >> 3);
    const int m0 = (flat / gx) * BM;
    const int n0 = (flat - (flat / gx) * gx) * BN;

    const int tid  = threadIdx.x;
    const int lane = tid & 63;
    const int wave = tid >> 6;
    const int wr   = wave >> 1, wc = wave & 1;
    const int ml   = lane & 15;
    const int q    = lane >> 4;

    // B staging pointers (swizzled)
    const bf16* Bb = B + (size_t)batch * sB;
    const bf16* bp[BSH];
#pragma unroll
    for (int s = 0; s < BSH; ++s) {
        int idx = s * 256 + tid;
        int row = idx >> 2, cg = idx & 3;
        bp[s] = Bb + (size_t)(n0 + row) * K + k0 + 8 * bswz(row, cg);
    }

    // A staging pointers (swizzled)
    const float* a32[4];
    const bf16*  a16[2];
    if constexpr (A_F32) {
        const float* Ab = (const float*)Av + (size_t)batch * sA;
#pragma unroll
        for (int s = 0; s < 4; ++s) {
            int idx = s * 256 + tid;
            int row = idx >> 3, cg = idx & 7;
            a32[s] = Ab + (size_t)(m0 + row) * K + k0 + 4 * fswz(row, cg);
        }
    } else {
        const bf16* Ab = (const bf16*)Av + (size_t)batch * sA;
#pragma unroll
        for (int s = 0; s < 2; ++s) {
            int idx = s * 256 + tid;
            int row = idx >> 2, cg = idx & 3;
            a16[s] = Ab + (size_t)(m0 + row) * K + k0 + 8 * bswz(row, cg);
        }
    }

    f32x4 acc[4][NFRAG] = {};

    // stage tile into LDS buffer `buf`, advance pointers by BK
    auto stage = [&](int buf) {
        if constexpr (A_F32) {
            float* lAf = (float*)lA[buf];
#pragma unroll
            for (int s = 0; s < 4; ++s) {
                g2lds16(a32[s], &lAf[(s * 256 + tid) * 4]);
                a32[s] += BK;
            }
        } else {
#pragma unroll
            for (int s = 0; s < 2; ++s) {
                g2lds16(a16[s], &lA[buf][(s * 256 + tid) * 8]);
                a16[s] += BK;
            }
        }
#pragma unroll
        for (int s = 0; s < BSH; ++s) {
            g2lds16(bp[s], &lB[buf][(s * 256 + tid) * 8]);
            bp[s] += BK;
        }
    };

    // ds_read fragments from buffer `buf` and run the MFMA cluster
    auto compute = [&](int buf) {
        const bf16* cA = lA[buf];
        const bf16* cB = lB[buf];
        short8 af[4], bfr[NFRAG];
#pragma unroll
        for (int i = 0; i < 4; ++i) {
            const int rA = wr * 64 + i * 16 + ml;
            if constexpr (A_F32) {
                const float* lAf = (const float*)cA;
                float4 x0 = *(const float4*)&lAf[rA * 32 + 4 * fswz(rA, 2 * q)];
                float4 x1 = *(const float4*)&lAf[rA * 32 + 4 * fswz(rA, 2 * q + 1)];
                af[i][0] = f2bs(x0.x); af[i][1] = f2bs(x0.y);
                af[i][2] = f2bs(x0.z); af[i][3] = f2bs(x0.w);
                af[i][4] = f2bs(x1.x); af[i][5] = f2bs(x1.y);
                af[i][6] = f2bs(x1.z); af[i][7] = f2bs(x1.w);
            } else {
                af[i] = *(const short8*)&cA[rA * 32 + 8 * bswz(rA, q)];
            }
        }
#pragma unroll
        for (int j = 0; j < NFRAG; ++j) {
            const int rB = wc * (16 * NFRAG) + j * 16 + ml;
            bfr[j] = *(const short8*)&cB[rB * 32 + 8 * bswz(rB, q)];
        }
#pragma unroll
        for (int mi = 0; mi < 4; ++mi)
#pragma unroll
            for (int nj = 0; nj < NFRAG; ++nj)
                acc[mi][nj] = __builtin_amdgcn_mfma_f32_16x16x32_bf16(
                    af[mi], bfr[nj], acc[mi][nj], 0, 0, 0);
    };

    const int nk = kLen / BK;
    // prologue: fill buffer 0
    stage(0);
    __syncthreads();                 // vmcnt(0) drain — only full-latency wait
    int cur = 0;
    for (int kt = 0; kt < nk - 1; ++kt) {
        stage(cur ^ 1);              // issue next tile's loads FIRST
        compute(cur);                // MFMA hides the load flight time
        __syncthreads();             // one barrier/step: drains stage, guards reuse
        cur ^= 1;
    }
    compute(cur);                    // last tile, no prefetch

    // epilogue: C/D layout col=lane&15, row=(lane>>4)*4+r (m89-verified)
#pragma unroll
    for (int mi = 0; mi < 4; ++mi)
#pragma unroll
        for (int nj = 0; nj < NFRAG; ++nj)
#pragma unroll
            for (int r = 0; r < 4; ++r) {
                int row = m0 + wr * 64 + mi * 16 + q * 4 + r;
                int col = n0 + wc * (16 * NFRAG) + nj * 16 + ml;
                if constexpr (MODE == 1) {
                    float* Cf = (float*)Cv + (size_t)batch * sC;
                    atomicAdd(&Cf[(size_t)row * N + col], acc[mi][nj][r]);
                } else if constexpr (MODE == 0) {
                    ushort* Cb = (ushort*)Cv + (size_t)batch * sC;
                    Cb[(size_t)row * N + col] = (ushort)f2bs(acc[mi][nj][r]);
                } else {
                    float* Cf = (float*)Cv + (size_t)batch * sC;
                    Cf[(size_t)row * N + col] = acc[mi][nj][r];
                }
            }
}

// ---------------------------------------------------------------
// fp32 I/O.  O = ((X W^T) X^T) X == X * (W^T (X^T X))   [associative]
//   G  = Xt * Xt^T   (split-K=4, fp32 atomic)     Xt = bf16(X)^T
//   Mt = Gf * Wt^T   (A fp32 staged, bf16 store)  Wt = bf16(W)^T
//   O  = X * Mt^T    (fp32 store; A = Xb bf16 if ws fits, else X fp32)
// d_out scratch (dead before step 7 overwrites):
//   Xt bf16 @0 (16M) | Gf f32 @16M (8M) | Wt @28M (2M)
// ws: [Xb bf16 16M if ws_size>=20M] + Mt bf16 4M.
// ---------------------------------------------------------------
extern "C" void kernel_launch(void* const* d_in, const int* in_sizes, int n_in,
                              void* d_out, int out_size, void* d_ws, size_t ws_size,
                              hipStream_t stream)
{
    const int B = 2, N = 4096, D = 1024;
    const float* X = (const float*)d_in[0];   // [B][N][D] fp32
    const float* W = (const float*)d_in[1];   // [D][D]    fp32
    float* out = (float*)d_out;               // [B][N][D] fp32

    char* ob = (char*)d_out;
    char* ws = (char*)d_ws;
    ushort* Xt = (ushort*)ob;                  // [B][D][N] bf16, 16 MiB
    float*  Gf = (float*)(ob + (16ll << 20));  // [B][D][D] fp32,  8 MiB
    ushort* Wt = (ushort*)(ob + (28ll << 20)); // [D][D]    bf16,  2 MiB

    const bool bigws = ws_size >= (20ull << 20);
    ushort* Xb = bigws ? (ushort*)ws : nullptr;             // [B][N][D] bf16, 16 MiB
    ushort* Mt = (ushort*)(ws + (bigws ? (16ll << 20) : 0)); // [B][D][D] bf16, 4 MiB

    // 1) Xt[b] = bf16(X[b])^T  (+ Xb = bf16(X) row-major when ws allows)
    transpose_cvt<<<dim3(D / 64, N / 64, B), 256, 0, stream>>>(
        X, Xt, Xb, N, D, (long)N * D, (long)D * N, (long)N * D);
    // 2) Wt = bf16(W)^T
    transpose_cvt<<<dim3(D / 64, D / 64, 1), 256, 0, stream>>>(
        W, Wt, nullptr, D, D, 0, 0, 0);
    // 3) zero split-K accumulator
    (void)hipMemsetAsync(Gf, 0, (size_t)B * D * D * sizeof(float), stream);
    // 4) Gf[b] += Xt[b] * Xt[b]^T   (M=N=D, K=4096, split-K 4, BN=128)
    gemm_bt<1, 0, 4><<<dim3(D / 128, D / BM, B * 4), 256, 0, stream>>>(
        (const void*)Xt, (const bf16*)Xt, Gf, D, D, N, 4,
        (long)D * N, (long)D * N, (long)D * D);
    // 6) Mt[b] = Gf[b] * Wt^T   (M=N=K=D, BN=64, A fp32 staged)
    gemm_bt<0, 1, 2><<<dim3(D / 64, D / BM, B), 256, 0, stream>>>(
        (const void*)Gf, (const bf16*)Wt, Mt, D, D, D, 1,
        (long)D * D, 0, (long)D * D);
    // 7) O[b] = X[b] * Mt[b]^T  (M=4096, N=D, K=D, BN=128; overwrites d_out)
    if (bigws) {
        gemm_bt<2, 0, 4><<<dim3(D / 128, N / BM, B), 256, 0, stream>>>(
            (const void*)Xb, (const bf16*)Mt, out, N, D, D, 1,
            (long)N * D, (long)D * D, (long)N * D);
    } else {
        gemm_bt<2, 1, 4><<<dim3(D / 128, N / BM, B), 256, 0, stream>>>(
            (const void*)X, (const bf16*)Mt, out, N, D, D, 1,
            (long)N * D, (long)D * D, (long)N * D);
    }
}

// Round 4
// 182.569 us; speedup vs baseline: 1.1297x; 1.1125x over previous
//
#include <hip/hip_runtime.h>
#include <hip/hip_bf16.h>
#include <stdint.h>

using bf16 = __hip_bfloat16;
typedef __attribute__((ext_vector_type(8))) short short8;
typedef __attribute__((ext_vector_type(4))) float f32x4;

#define BM 128
#define BK 32

// -------- async global->LDS, 16B per lane (m97 pattern) --------
__device__ __forceinline__ void g2lds16(const void* g, void* l) {
    __builtin_amdgcn_global_load_lds(
        (const __attribute__((address_space(1))) void*)g,
        (__attribute__((address_space(3))) void*)l,
        16, 0, 0);
}

template <int N>
__device__ __forceinline__ void s_wait_vmcnt() {
    asm volatile("s_waitcnt vmcnt(%0)" :: "n"(N) : "memory");
}
__device__ __forceinline__ void s_wait_lgkm0() {
    asm volatile("s_waitcnt lgkmcnt(0)" ::: "memory");
    __builtin_amdgcn_sched_barrier(0);
}

__device__ __forceinline__ short f2bs(float x) {
    union { bf16 h; short s; } u;
    u.h = __float2bfloat16(x);
    return u.s;
}

// ---- LDS XOR swizzles (conflict-free fragment reads) ----
// bf16 tile [rows][32 bf16] = 4 groups/row of 8 bf16 (16B). s=(row>>1)&3.
__device__ __forceinline__ int bswz(int row, int cg) { return cg ^ ((row >> 1) & 3); }
// fp32 tile [rows][32 f32] = 8 groups/row of 4 f32 (16B). s=row&7.
__device__ __forceinline__ int fswz(int row, int cg) { return cg ^ (row & 7); }

// ---- fp32 -> bf16 64x64 tile transpose (+ optional row-major bf16 copy) ----
__global__ __launch_bounds__(256)
void transpose_cvt(const float* __restrict__ src, ushort* __restrict__ dstT,
                   ushort* __restrict__ dstN,
                   int R, int C, long sstride, long dstrideT, long dstrideN)
{
    __shared__ __align__(16) ushort t[64][72];
    const float* s = src + (size_t)blockIdx.z * sstride;
    ushort*      dT = dstT + (size_t)blockIdx.z * dstrideT;
    const int r0 = blockIdx.y * 64, c0 = blockIdx.x * 64;
    const int tid = threadIdx.x;
#pragma unroll
    for (int ii = 0; ii < 4; ++ii) {
        int idx = ii * 256 + tid;
        int r = idx >> 4, c4 = (idx & 15) * 4;
        float4 v = *(const float4*)&s[(size_t)(r0 + r) * C + c0 + c4];
        union { ushort u[4]; uint2 q; } o;
        o.u[0] = (ushort)f2bs(v.x); o.u[1] = (ushort)f2bs(v.y);
        o.u[2] = (ushort)f2bs(v.z); o.u[3] = (ushort)f2bs(v.w);
        *(uint2*)&t[r][c4] = o.q;
        if (dstN) {
            ushort* dN = dstN + (size_t)blockIdx.z * dstrideN;
            *(uint2*)&dN[(size_t)(r0 + r) * C + c0 + c4] = o.q;
        }
    }
    __syncthreads();
#pragma unroll
    for (int ii = 0; ii < 2; ++ii) {
        int idx = ii * 256 + tid;
        int c = idx >> 3, r8 = (idx & 7) * 8;
        union { ushort u[8]; uint4 v; } tmp;
#pragma unroll
        for (int j = 0; j < 8; ++j) tmp.u[j] = t[r8 + j][c];
        *(uint4*)&dT[(size_t)(c0 + c) * R + r0 + r8] = tmp.v;
    }
}

// -------- C = A * B^T ; A:[M][K], B:[N][K] row-major, k contiguous --------
// MODE 0: bf16 store. MODE 1: fp32 atomicAdd (split-K). MODE 2: fp32 store.
// A_F32: A operand fp32 in global (staged fp32, cvt at frag load).
// NFRAG: n-fragments (16-wide) per wave; BN = 32*NFRAG.
// Round 3: T4 counted-vmcnt pipeline. 3 LDS buffers, 2 raw s_barriers per
// K-step, NEVER vmcnt(0) in steady state (issue-to-wait distance = 3 steps).
// Invariants: vmcnt(2L) => S(t) retired (FIFO); barrier AFTER wait publishes
// tile to all waves; lgkmcnt(0)+barrier BEFORE re-staging protects readers.
// Requires nk >= 3 (all call sites have nk == 32).
template <int MODE, int A_F32, int NFRAG>
__global__ __launch_bounds__(256)
void gemm_bt(const void* __restrict__ Av, const bf16* __restrict__ B,
             void* __restrict__ Cv, int M, int N, int K, int kChunks,
             long sA, long sB, long sC)
{
    constexpr int BN  = 32 * NFRAG;
    constexpr int BSH = BN / 64;                    // B staging shots
    constexpr int ASH = A_F32 ? 4 : 2;              // A staging shots
    constexpr int L   = ASH + BSH;                  // loads per stage per thread
    constexpr int ANE = BM * BK * (A_F32 ? 2 : 1);  // bf16 elems per A buffer
    __shared__ __align__(16) bf16 lA[3][ANE];
    __shared__ __align__(16) bf16 lB[3][BN * BK];

    const int z     = blockIdx.z;
    const int batch = z / kChunks;
    const int chunk = z - batch * kChunks;
    const int kLen  = K / kChunks;
    const int k0    = chunk * kLen;

    // XCD-aware chunked swizzle of flattened (x,y); bijective since nxy%8==0
    const int gx  = gridDim.x;
    int flat = blockIdx.y * gx + blockIdx.x;
    const int cpx = (gx * gridDim.y) >> 3;
    flat = (flat & 7) * cpx + (flat >> 3);
    const int m0 = (flat / gx) * BM;
    const int n0 = (flat - (flat / gx) * gx) * BN;

    const int tid  = threadIdx.x;
    const int lane = tid & 63;
    const int wave = tid >> 6;
    const int wr   = wave >> 1, wc = wave & 1;
    const int ml   = lane & 15;
    const int q    = lane >> 4;

    // B staging pointers (swizzled)
    const bf16* Bb = B + (size_t)batch * sB;
    const bf16* bp[BSH];
#pragma unroll
    for (int s = 0; s < BSH; ++s) {
        int idx = s * 256 + tid;
        int row = idx >> 2, cg = idx & 3;
        bp[s] = Bb + (size_t)(n0 + row) * K + k0 + 8 * bswz(row, cg);
    }

    // A staging pointers (swizzled)
    const float* a32[4];
    const bf16*  a16[2];
    if constexpr (A_F32) {
        const float* Ab = (const float*)Av + (size_t)batch * sA;
#pragma unroll
        for (int s = 0; s < 4; ++s) {
            int idx = s * 256 + tid;
            int row = idx >> 3, cg = idx & 7;
            a32[s] = Ab + (size_t)(m0 + row) * K + k0 + 4 * fswz(row, cg);
        }
    } else {
        const bf16* Ab = (const bf16*)Av + (size_t)batch * sA;
#pragma unroll
        for (int s = 0; s < 2; ++s) {
            int idx = s * 256 + tid;
            int row = idx >> 2, cg = idx & 3;
            a16[s] = Ab + (size_t)(m0 + row) * K + k0 + 8 * bswz(row, cg);
        }
    }

    f32x4 acc[4][NFRAG] = {};

    // stage next tile into LDS buffer `buf`, advance pointers by BK
    auto stage = [&](int buf) {
        if constexpr (A_F32) {
            float* lAf = (float*)lA[buf];
#pragma unroll
            for (int s = 0; s < 4; ++s) {
                g2lds16(a32[s], &lAf[(s * 256 + tid) * 4]);
                a32[s] += BK;
            }
        } else {
#pragma unroll
            for (int s = 0; s < 2; ++s) {
                g2lds16(a16[s], &lA[buf][(s * 256 + tid) * 8]);
                a16[s] += BK;
            }
        }
#pragma unroll
        for (int s = 0; s < BSH; ++s) {
            g2lds16(bp[s], &lB[buf][(s * 256 + tid) * 8]);
            bp[s] += BK;
        }
    };

    // consume buffer `buf`: ds_read frags, publish-read fence, optional
    // re-stage of the SAME buffer (tile t+3), then MFMA cluster.
    auto step = [&](int buf, bool doStage) {
        const bf16* cA = lA[buf];
        const bf16* cB = lB[buf];
        short8 af[4], bfr[NFRAG];
#pragma unroll
        for (int i = 0; i < 4; ++i) {
            const int rA = wr * 64 + i * 16 + ml;
            if constexpr (A_F32) {
                const float* lAf = (const float*)cA;
                float4 x0 = *(const float4*)&lAf[rA * 32 + 4 * fswz(rA, 2 * q)];
                float4 x1 = *(const float4*)&lAf[rA * 32 + 4 * fswz(rA, 2 * q + 1)];
                af[i][0] = f2bs(x0.x); af[i][1] = f2bs(x0.y);
                af[i][2] = f2bs(x0.z); af[i][3] = f2bs(x0.w);
                af[i][4] = f2bs(x1.x); af[i][5] = f2bs(x1.y);
                af[i][6] = f2bs(x1.z); af[i][7] = f2bs(x1.w);
            } else {
                af[i] = *(const short8*)&cA[rA * 32 + 8 * bswz(rA, q)];
            }
        }
#pragma unroll
        for (int j = 0; j < NFRAG; ++j) {
            const int rB = wc * (16 * NFRAG) + j * 16 + ml;
            bfr[j] = *(const short8*)&cB[rB * 32 + 8 * bswz(rB, q)];
        }
        s_wait_lgkm0();                      // frags in regs (rule #18 fence)
        __builtin_amdgcn_s_barrier();        // all waves done reading buf
        if (doStage) stage(buf);             // tile t+3 overwrites buf
        __builtin_amdgcn_s_setprio(1);
#pragma unroll
        for (int mi = 0; mi < 4; ++mi)
#pragma unroll
            for (int nj = 0; nj < NFRAG; ++nj)
                acc[mi][nj] = __builtin_amdgcn_mfma_f32_16x16x32_bf16(
                    af[mi], bfr[nj], acc[mi][nj], 0, 0, 0);
        __builtin_amdgcn_s_setprio(0);
    };

    const int nk = kLen / BK;
    // prologue: 3 tiles in flight
    stage(0); stage(1); stage(2);
    int cur = 0;
    for (int kt = 0; kt < nk - 2; ++kt) {
        s_wait_vmcnt<2 * L>();               // S(t) landed, S(t+1..t+2) in flight
        __builtin_amdgcn_s_barrier();        // tile t visible to all waves
        step(cur, kt < nk - 3);
        cur = (cur == 2) ? 0 : cur + 1;
    }
    s_wait_vmcnt<L>();                       // S(nk-2) landed
    __builtin_amdgcn_s_barrier();
    step(cur, false);
    cur = (cur == 2) ? 0 : cur + 1;
    s_wait_vmcnt<0>();                       // S(nk-1) landed (tail only)
    __builtin_amdgcn_s_barrier();
    step(cur, false);

    // epilogue: C/D layout col=lane&15, row=(lane>>4)*4+r (m89-verified)
#pragma unroll
    for (int mi = 0; mi < 4; ++mi)
#pragma unroll
        for (int nj = 0; nj < NFRAG; ++nj)
#pragma unroll
            for (int r = 0; r < 4; ++r) {
                int row = m0 + wr * 64 + mi * 16 + q * 4 + r;
                int col = n0 + wc * (16 * NFRAG) + nj * 16 + ml;
                if constexpr (MODE == 1) {
                    float* Cf = (float*)Cv + (size_t)batch * sC;
                    atomicAdd(&Cf[(size_t)row * N + col], acc[mi][nj][r]);
                } else if constexpr (MODE == 0) {
                    ushort* Cb = (ushort*)Cv + (size_t)batch * sC;
                    Cb[(size_t)row * N + col] = (ushort)f2bs(acc[mi][nj][r]);
                } else {
                    float* Cf = (float*)Cv + (size_t)batch * sC;
                    Cf[(size_t)row * N + col] = acc[mi][nj][r];
                }
            }
}

// ---------------------------------------------------------------
// fp32 I/O.  O = ((X W^T) X^T) X == X * (W^T (X^T X))   [associative]
//   G  = Xt * Xt^T   (split-K=4, fp32 atomic)     Xt = bf16(X)^T
//   Mt = Gf * Wt^T   (A fp32 staged, bf16 store)  Wt = bf16(W)^T
//   O  = X * Mt^T    (fp32 store; A = Xb bf16 if ws fits, else X fp32)
// d_out scratch (dead before step 7 overwrites):
//   Xt bf16 @0 (16M) | Gf f32 @16M (8M) | Wt @28M (2M)
// ws: [Xb bf16 16M if ws_size>=20M] + Mt bf16 4M.
// ---------------------------------------------------------------
extern "C" void kernel_launch(void* const* d_in, const int* in_sizes, int n_in,
                              void* d_out, int out_size, void* d_ws, size_t ws_size,
                              hipStream_t stream)
{
    const int B = 2, N = 4096, D = 1024;
    const float* X = (const float*)d_in[0];   // [B][N][D] fp32
    const float* W = (const float*)d_in[1];   // [D][D]    fp32
    float* out = (float*)d_out;               // [B][N][D] fp32

    char* ob = (char*)d_out;
    char* ws = (char*)d_ws;
    ushort* Xt = (ushort*)ob;                  // [B][D][N] bf16, 16 MiB
    float*  Gf = (float*)(ob + (16ll << 20));  // [B][D][D] fp32,  8 MiB
    ushort* Wt = (ushort*)(ob + (28ll << 20)); // [D][D]    bf16,  2 MiB

    const bool bigws = ws_size >= (20ull << 20);
    ushort* Xb = bigws ? (ushort*)ws : nullptr;             // [B][N][D] bf16, 16 MiB
    ushort* Mt = (ushort*)(ws + (bigws ? (16ll << 20) : 0)); // [B][D][D] bf16, 4 MiB

    // 1) Xt[b] = bf16(X[b])^T  (+ Xb = bf16(X) row-major when ws allows)
    transpose_cvt<<<dim3(D / 64, N / 64, B), 256, 0, stream>>>(
        X, Xt, Xb, N, D, (long)N * D, (long)D * N, (long)N * D);
    // 2) Wt = bf16(W)^T
    transpose_cvt<<<dim3(D / 64, D / 64, 1), 256, 0, stream>>>(
        W, Wt, nullptr, D, D, 0, 0, 0);
    // 3) zero split-K accumulator
    (void)hipMemsetAsync(Gf, 0, (size_t)B * D * D * sizeof(float), stream);
    // 4) Gf[b] += Xt[b] * Xt[b]^T   (M=N=D, K=4096, split-K 4, BN=128)
    gemm_bt<1, 0, 4><<<dim3(D / 128, D / BM, B * 4), 256, 0, stream>>>(
        (const void*)Xt, (const bf16*)Xt, Gf, D, D, N, 4,
        (long)D * N, (long)D * N, (long)D * D);
    // 6) Mt[b] = Gf[b] * Wt^T   (M=N=K=D, BN=64, A fp32 staged)
    gemm_bt<0, 1, 2><<<dim3(D / 64, D / BM, B), 256, 0, stream>>>(
        (const void*)Gf, (const bf16*)Wt, Mt, D, D, D, 1,
        (long)D * D, 0, (long)D * D);
    // 7) O[b] = X[b] * Mt[b]^T  (M=4096, N=D, K=D, BN=128; overwrites d_out)
    if (bigws) {
        gemm_bt<2, 0, 4><<<dim3(D / 128, N / BM, B), 256, 0, stream>>>(
            (const void*)Xb, (const bf16*)Mt, out, N, D, D, 1,
            (long)N * D, (long)D * D, (long)N * D);
    } else {
        gemm_bt<2, 1, 4><<<dim3(D / 128, N / BM, B), 256, 0, stream>>>(
            (const void*)X, (const bf16*)Mt, out, N, D, D, 1,
            (long)N * D, (long)D * D, (long)N * D);
    }
}

// Round 5
// 174.710 us; speedup vs baseline: 1.1805x; 1.0450x over previous
//
#include <hip/hip_runtime.h>
#include <hip/hip_bf16.h>
#include <stdint.h>

using bf16 = __hip_bfloat16;
typedef __attribute__((ext_vector_type(8))) short short8;
typedef __attribute__((ext_vector_type(4))) float f32x4;

#define BM 128
#define BK 32

template <int V> struct ic { static constexpr int v = V; };

// -------- async global->LDS, 16B per lane (m97 pattern) --------
__device__ __forceinline__ void g2lds16(const void* g, void* l) {
    __builtin_amdgcn_global_load_lds(
        (const __attribute__((address_space(1))) void*)g,
        (__attribute__((address_space(3))) void*)l,
        16, 0, 0);
}

template <int N>
__device__ __forceinline__ void s_wait_vmcnt() {
    asm volatile("s_waitcnt vmcnt(%0)" :: "n"(N) : "memory");
}

__device__ __forceinline__ short f2bs(float x) {
    union { bf16 h; short s; } u;
    u.h = __float2bfloat16(x);
    return u.s;
}

// ---- LDS XOR swizzles (conflict-free fragment reads) ----
// bf16 tile [rows][32 bf16] = 4 groups/row of 8 bf16 (16B). s=(row>>1)&3.
__device__ __forceinline__ int bswz(int row, int cg) { return cg ^ ((row >> 1) & 3); }
// fp32 tile [rows][32 f32] = 8 groups/row of 4 f32 (16B). s=row&7.
__device__ __forceinline__ int fswz(int row, int cg) { return cg ^ (row & 7); }

// ---- fp32 -> bf16 64x64 tile transpose (+ optional row-major bf16 copy) ----
__global__ __launch_bounds__(256)
void transpose_cvt(const float* __restrict__ src, ushort* __restrict__ dstT,
                   ushort* __restrict__ dstN,
                   int R, int C, long sstride, long dstrideT, long dstrideN)
{
    __shared__ __align__(16) ushort t[64][72];
    const float* s = src + (size_t)blockIdx.z * sstride;
    ushort*      dT = dstT + (size_t)blockIdx.z * dstrideT;
    const int r0 = blockIdx.y * 64, c0 = blockIdx.x * 64;
    const int tid = threadIdx.x;
#pragma unroll
    for (int ii = 0; ii < 4; ++ii) {
        int idx = ii * 256 + tid;
        int r = idx >> 4, c4 = (idx & 15) * 4;
        float4 v = *(const float4*)&s[(size_t)(r0 + r) * C + c0 + c4];
        union { ushort u[4]; uint2 q; } o;
        o.u[0] = (ushort)f2bs(v.x); o.u[1] = (ushort)f2bs(v.y);
        o.u[2] = (ushort)f2bs(v.z); o.u[3] = (ushort)f2bs(v.w);
        *(uint2*)&t[r][c4] = o.q;
        if (dstN) {
            ushort* dN = dstN + (size_t)blockIdx.z * dstrideN;
            *(uint2*)&dN[(size_t)(r0 + r) * C + c0 + c4] = o.q;
        }
    }
    __syncthreads();
#pragma unroll
    for (int ii = 0; ii < 2; ++ii) {
        int idx = ii * 256 + tid;
        int c = idx >> 3, r8 = (idx & 7) * 8;
        union { ushort u[8]; uint4 v; } tmp;
#pragma unroll
        for (int j = 0; j < 8; ++j) tmp.u[j] = t[r8 + j][c];
        *(uint4*)&dT[(size_t)(c0 + c) * R + r0 + r8] = tmp.v;
    }
}

// -------- C = A * B^T ; A:[M][K], B:[N][K] row-major, k contiguous --------
// MODE 0: bf16 store. MODE 1: fp32 atomicAdd (split-K). MODE 2: fp32 store.
// A_F32: A operand fp32 in global (staged fp32, cvt at frag load).
// NFRAG: n-fragments (16-wide) per wave; BN = 32*NFRAG.
// Round 4: 4 static LDS buffers (distance-3 stage never touches a buffer
// being read) -> ONE s_barrier per K-step, counted vmcnt, NO lgkm drain
// between ds_read and MFMA (compiler emits fine-grained lgkmcnt waits and
// interleaves reads with MFMAs). Trailing lgkmcnt(0) before the next
// barrier closes the cross-wave WAR race (buf read at t is re-staged at
// t+1 by waves that passed the t+1 barrier). Requires nk%4==0, nk>=8.
template <int MODE, int A_F32, int NFRAG>
__global__ __launch_bounds__(256)
void gemm_bt(const void* __restrict__ Av, const bf16* __restrict__ B,
             void* __restrict__ Cv, int M, int N, int K, int kChunks,
             long sA, long sB, long sC)
{
    constexpr int BN  = 32 * NFRAG;
    constexpr int BSH = BN / 64;                    // B staging shots
    constexpr int ASH = A_F32 ? 4 : 2;              // A staging shots
    constexpr int L   = ASH + BSH;                  // vmcnt events per stage
    constexpr int ANE = BM * BK * (A_F32 ? 2 : 1);  // bf16 elems per A buffer
    constexpr int BNE = BN * BK;
    __shared__ __align__(16) bf16 lA0[ANE], lA1[ANE], lA2[ANE], lA3[ANE];
    __shared__ __align__(16) bf16 lB0[BNE], lB1[BNE], lB2[BNE], lB3[BNE];

    const int z     = blockIdx.z;
    const int batch = z / kChunks;
    const int chunk = z - batch * kChunks;
    const int kLen  = K / kChunks;
    const int k0    = chunk * kLen;

    // XCD-aware chunked swizzle of flattened (x,y); bijective since nxy%8==0
    const int gx  = gridDim.x;
    int flat = blockIdx.y * gx + blockIdx.x;
    const int cpx = (gx * gridDim.y) >> 3;
    flat = (flat & 7) * cpx + (flat >> 3);
    const int m0 = (flat / gx) * BM;
    const int n0 = (flat - (flat / gx) * gx) * BN;

    const int tid  = threadIdx.x;
    const int lane = tid & 63;
    const int wave = tid >> 6;
    const int wr   = wave >> 1, wc = wave & 1;
    const int ml   = lane & 15;
    const int q    = lane >> 4;

    // B staging pointers (swizzled)
    const bf16* Bb = B + (size_t)batch * sB;
    const bf16* bp[BSH];
#pragma unroll
    for (int s = 0; s < BSH; ++s) {
        int idx = s * 256 + tid;
        int row = idx >> 2, cg = idx & 3;
        bp[s] = Bb + (size_t)(n0 + row) * K + k0 + 8 * bswz(row, cg);
    }

    // A staging pointers (swizzled)
    const float* a32[4];
    const bf16*  a16[2];
    if constexpr (A_F32) {
        const float* Ab = (const float*)Av + (size_t)batch * sA;
#pragma unroll
        for (int s = 0; s < 4; ++s) {
            int idx = s * 256 + tid;
            int row = idx >> 3, cg = idx & 7;
            a32[s] = Ab + (size_t)(m0 + row) * K + k0 + 4 * fswz(row, cg);
        }
    } else {
        const bf16* Ab = (const bf16*)Av + (size_t)batch * sA;
#pragma unroll
        for (int s = 0; s < 2; ++s) {
            int idx = s * 256 + tid;
            int row = idx >> 2, cg = idx & 3;
            a16[s] = Ab + (size_t)(m0 + row) * K + k0 + 8 * bswz(row, cg);
        }
    }

    f32x4 acc[4][NFRAG] = {};

    auto pickA = [&](auto C) -> bf16* {
        constexpr int b_ = decltype(C)::v;
        if constexpr (b_ == 0) return lA0;
        else if constexpr (b_ == 1) return lA1;
        else if constexpr (b_ == 2) return lA2;
        else return lA3;
    };
    auto pickB = [&](auto C) -> bf16* {
        constexpr int b_ = decltype(C)::v;
        if constexpr (b_ == 0) return lB0;
        else if constexpr (b_ == 1) return lB1;
        else if constexpr (b_ == 2) return lB2;
        else return lB3;
    };

    // stage next tile into compile-time buffer, advance pointers by BK
    auto stage = [&](auto C) {
        bf16* A_ = pickA(C);
        bf16* B_ = pickB(C);
        if constexpr (A_F32) {
            float* lAf = (float*)A_;
#pragma unroll
            for (int s = 0; s < 4; ++s) {
                g2lds16(a32[s], &lAf[(s * 256 + tid) * 4]);
                a32[s] += BK;
            }
        } else {
#pragma unroll
            for (int s = 0; s < 2; ++s) {
                g2lds16(a16[s], &A_[(s * 256 + tid) * 8]);
                a16[s] += BK;
            }
        }
#pragma unroll
        for (int s = 0; s < BSH; ++s) {
            g2lds16(bp[s], &B_[(s * 256 + tid) * 8]);
            bp[s] += BK;
        }
    };

    // read fragments from compile-time buffer (plain loads; compiler
    // schedules fine-grained lgkm waits against the MFMAs)
    auto frags = [&](auto C, short8 (&af)[4], short8 (&bfr)[NFRAG]) {
        const bf16* cA = pickA(C);
        const bf16* cB = pickB(C);
#pragma unroll
        for (int i = 0; i < 4; ++i) {
            const int rA = wr * 64 + i * 16 + ml;
            if constexpr (A_F32) {
                const float* lAf = (const float*)cA;
                float4 x0 = *(const float4*)&lAf[rA * 32 + 4 * fswz(rA, 2 * q)];
                float4 x1 = *(const float4*)&lAf[rA * 32 + 4 * fswz(rA, 2 * q + 1)];
                af[i][0] = f2bs(x0.x); af[i][1] = f2bs(x0.y);
                af[i][2] = f2bs(x0.z); af[i][3] = f2bs(x0.w);
                af[i][4] = f2bs(x1.x); af[i][5] = f2bs(x1.y);
                af[i][6] = f2bs(x1.z); af[i][7] = f2bs(x1.w);
            } else {
                af[i] = *(const short8*)&cA[rA * 32 + 8 * bswz(rA, q)];
            }
        }
#pragma unroll
        for (int j = 0; j < NFRAG; ++j) {
            const int rB = wc * (16 * NFRAG) + j * 16 + ml;
            bfr[j] = *(const short8*)&cB[rB * 32 + 8 * bswz(rB, q)];
        }
    };

    auto mfma = [&](short8 (&af)[4], short8 (&bfr)[NFRAG]) {
#pragma unroll
        for (int mi = 0; mi < 4; ++mi)
#pragma unroll
            for (int nj = 0; nj < NFRAG; ++nj)
                acc[mi][nj] = __builtin_amdgcn_mfma_f32_16x16x32_bf16(
                    af[mi], bfr[nj], acc[mi][nj], 0, 0, 0);
    };

#define GB_STEP(BUF, DOSTAGE, VM)                                        \
    do {                                                                 \
        s_wait_vmcnt<(VM)>();                                            \
        __builtin_amdgcn_s_barrier();                                    \
        short8 af_[4], bf_[NFRAG];                                       \
        frags(ic<BUF>{}, af_, bf_);                                      \
        if (DOSTAGE) stage(ic<(BUF + 3) & 3>{});                         \
        mfma(af_, bf_);                                                  \
        asm volatile("s_waitcnt lgkmcnt(0)" ::: "memory");               \
    } while (0)

    const int nk = kLen / BK;        // all call sites: 32 (nk%4==0, nk>=8)
    stage(ic<0>{}); stage(ic<1>{}); stage(ic<2>{});   // 3 tiles in flight
    for (int t4 = 0; t4 < nk / 4 - 1; ++t4) {
        GB_STEP(0, 1, 2 * L);
        GB_STEP(1, 1, 2 * L);
        GB_STEP(2, 1, 2 * L);
        GB_STEP(3, 1, 2 * L);
    }
    GB_STEP(0, 1, 2 * L);            // t=nk-4: stages tile nk-1 into buf 3
    GB_STEP(1, 0, 2 * L);            // t=nk-3
    GB_STEP(2, 0, L);                // t=nk-2
    GB_STEP(3, 0, 0);                // t=nk-1
#undef GB_STEP

    // epilogue: C/D layout col=lane&15, row=(lane>>4)*4+r (m89-verified)
#pragma unroll
    for (int mi = 0; mi < 4; ++mi)
#pragma unroll
        for (int nj = 0; nj < NFRAG; ++nj)
#pragma unroll
            for (int r = 0; r < 4; ++r) {
                int row = m0 + wr * 64 + mi * 16 + q * 4 + r;
                int col = n0 + wc * (16 * NFRAG) + nj * 16 + ml;
                if constexpr (MODE == 1) {
                    float* Cf = (float*)Cv + (size_t)batch * sC;
                    atomicAdd(&Cf[(size_t)row * N + col], acc[mi][nj][r]);
                } else if constexpr (MODE == 0) {
                    ushort* Cb = (ushort*)Cv + (size_t)batch * sC;
                    Cb[(size_t)row * N + col] = (ushort)f2bs(acc[mi][nj][r]);
                } else {
                    float* Cf = (float*)Cv + (size_t)batch * sC;
                    Cf[(size_t)row * N + col] = acc[mi][nj][r];
                }
            }
}

// ---------------------------------------------------------------
// fp32 I/O.  O = ((X W^T) X^T) X == X * (W^T (X^T X))   [associative]
//   G  = Xt * Xt^T   (split-K=4, fp32 atomic)     Xt = bf16(X)^T
//   Mt = Gf * Wt^T   (A fp32 staged, bf16 store)  Wt = bf16(W)^T
//   O  = X * Mt^T    (fp32 store; A = Xb bf16 if ws fits, else X fp32)
// d_out scratch (dead before step 7 overwrites):
//   Xt bf16 @0 (16M) | Gf f32 @16M (8M) | Wt @28M (2M)
// ws: [Xb bf16 16M if ws_size>=20M] + Mt bf16 4M.
// ---------------------------------------------------------------
extern "C" void kernel_launch(void* const* d_in, const int* in_sizes, int n_in,
                              void* d_out, int out_size, void* d_ws, size_t ws_size,
                              hipStream_t stream)
{
    const int B = 2, N = 4096, D = 1024;
    const float* X = (const float*)d_in[0];   // [B][N][D] fp32
    const float* W = (const float*)d_in[1];   // [D][D]    fp32
    float* out = (float*)d_out;               // [B][N][D] fp32

    char* ob = (char*)d_out;
    char* ws = (char*)d_ws;
    ushort* Xt = (ushort*)ob;                  // [B][D][N] bf16, 16 MiB
    float*  Gf = (float*)(ob + (16ll << 20));  // [B][D][D] fp32,  8 MiB
    ushort* Wt = (ushort*)(ob + (28ll << 20)); // [D][D]    bf16,  2 MiB

    const bool bigws = ws_size >= (20ull << 20);
    ushort* Xb = bigws ? (ushort*)ws : nullptr;             // [B][N][D] bf16, 16 MiB
    ushort* Mt = (ushort*)(ws + (bigws ? (16ll << 20) : 0)); // [B][D][D] bf16, 4 MiB

    // 1) Xt[b] = bf16(X[b])^T  (+ Xb = bf16(X) row-major when ws allows)
    transpose_cvt<<<dim3(D / 64, N / 64, B), 256, 0, stream>>>(
        X, Xt, Xb, N, D, (long)N * D, (long)D * N, (long)N * D);
    // 2) Wt = bf16(W)^T
    transpose_cvt<<<dim3(D / 64, D / 64, 1), 256, 0, stream>>>(
        W, Wt, nullptr, D, D, 0, 0, 0);
    // 3) zero split-K accumulator
    (void)hipMemsetAsync(Gf, 0, (size_t)B * D * D * sizeof(float), stream);
    // 4) Gf[b] += Xt[b] * Xt[b]^T   (M=N=D, K=4096, split-K 4, BN=128)
    gemm_bt<1, 0, 4><<<dim3(D / 128, D / BM, B * 4), 256, 0, stream>>>(
        (const void*)Xt, (const bf16*)Xt, Gf, D, D, N, 4,
        (long)D * N, (long)D * N, (long)D * D);
    // 6) Mt[b] = Gf[b] * Wt^T   (M=N=K=D, BN=64, A fp32 staged)
    gemm_bt<0, 1, 2><<<dim3(D / 64, D / BM, B), 256, 0, stream>>>(
        (const void*)Gf, (const bf16*)Wt, Mt, D, D, D, 1,
        (long)D * D, 0, (long)D * D);
    // 7) O[b] = X[b] * Mt[b]^T  (M=4096, N=D, K=D, BN=128; overwrites d_out)
    if (bigws) {
        gemm_bt<2, 0, 4><<<dim3(D / 128, N / BM, B), 256, 0, stream>>>(
            (const void*)Xb, (const bf16*)Mt, out, N, D, D, 1,
            (long)N * D, (long)D * D, (long)N * D);
    } else {
        gemm_bt<2, 1, 4><<<dim3(D / 128, N / BM, B), 256, 0, stream>>>(
            (const void*)X, (const bf16*)Mt, out, N, D, D, 1,
            (long)N * D, (long)D * D, (long)N * D);
    }
}